// Round 7
// baseline (1189.518 us; speedup 1.0000x reference)
//
#include <hip/hip_runtime.h>

#define N_DIM 12288
#define D_DIM 16
#define TILE  256               // 256x256 tile of A per block
#define NTILE (N_DIM / TILE)    // 48 -> 2304 blocks
#define PROBE_OFF (64u << 20)   // probe sink at d_ws+64MB
#define PROBE_PASSES 5

typedef float f4 __attribute__((ext_vector_type(4)));
typedef unsigned u4 __attribute__((ext_vector_type(4)));

// out[0] = 0 (d_out is poisoned 0xAA before every timed call)
__global__ void zero_kernel(float* __restrict__ out) {
    out[0] = 0.0f;
}

// lmbd1 * (sum|U1| + sum|U2|)
__global__ void l1_kernel(const float* __restrict__ U1,
                          const float* __restrict__ U2,
                          const float* __restrict__ lmbd,
                          float* __restrict__ out) {
    const int M = N_DIM * D_DIM;
    int idx = blockIdx.x * blockDim.x + threadIdx.x;
    int stride = gridDim.x * blockDim.x;
    float s = 0.0f;
    for (int i = idx; i < M; i += stride)
        s += fabsf(U1[i]) + fabsf(U2[i]);
    #pragma unroll
    for (int off = 32; off; off >>= 1)
        s += __shfl_down(s, off, 64);
    __shared__ float ws[4];
    int lane = threadIdx.x & 63;
    int wave = threadIdx.x >> 6;
    if (lane == 0) ws[wave] = s;
    __syncthreads();
    if (threadIdx.x == 0)
        atomicAdd(out, lmbd[0] * (ws[0] + ws[1] + ws[2] + ws[3]));
}

// sum_ij A_ij * (-log_sigmoid(<U1_i,U2_j>)), single pass over A.
// (Unchanged from round 5 -- best-known structure, 747.7 us.)
__global__ __launch_bounds__(256, 4)
void loss_kernel(const float* __restrict__ A,
                 const float* __restrict__ U1,
                 const float* __restrict__ U2,
                 float* __restrict__ out) {
    const int t    = threadIdx.x;
    const int lane = t & 63;
    const int wave = t >> 6;
    const int r0   = blockIdx.y * TILE;
    const int c0   = blockIdx.x * TILE;

    float u2r[4][D_DIM];
    #pragma unroll
    for (int c = 0; c < 4; ++c) {
        const f4* p = (const f4*)(U2 + (size_t)(c0 + lane * 4 + c) * D_DIM);
        f4 qa = p[0], qb = p[1], qc = p[2], qd = p[3];
        u2r[c][0]  = qa.x; u2r[c][1]  = qa.y; u2r[c][2]  = qa.z; u2r[c][3]  = qa.w;
        u2r[c][4]  = qb.x; u2r[c][5]  = qb.y; u2r[c][6]  = qb.z; u2r[c][7]  = qb.w;
        u2r[c][8]  = qc.x; u2r[c][9]  = qc.y; u2r[c][10] = qc.z; u2r[c][11] = qc.w;
        u2r[c][12] = qd.x; u2r[c][13] = qd.y; u2r[c][14] = qd.z; u2r[c][15] = qd.w;
    }

    const int urow0 = __builtin_amdgcn_readfirstlane(r0 + wave * 64);
    const float* __restrict__ up = U1 + (size_t)urow0 * D_DIM;
    const float* __restrict__ ap =
        A + (size_t)(r0 + wave * 64) * N_DIM + (size_t)c0 + lane * 4;

    const float L2E = 1.4426950408889634f;
    float acc = 0.0f;

    f4 av[4], bv[4];

#define LOADG(buf, g)                                                          \
    { _Pragma("unroll")                                                        \
      for (int r = 0; r < 4; ++r)                                              \
          buf[r] = __builtin_nontemporal_load(                                 \
              (const f4*)(ap + (size_t)(4 * (g) + r) * N_DIM)); }

#define COMPG(buf, g)                                                          \
    { float p0 = 1.0f, p1 = 1.0f, p2 = 1.0f, p3 = 1.0f;                        \
      _Pragma("unroll")                                                        \
      for (int r = 0; r < 4; ++r) {                                            \
          const float* u = up + (size_t)(4 * (g) + r) * D_DIM;                 \
          float s0 = 0.f, s1 = 0.f, s2 = 0.f, s3 = 0.f;                        \
          _Pragma("unroll")                                                    \
          for (int k = 0; k < D_DIM; ++k) {                                    \
              float uk = u[k];                                                 \
              s0 = fmaf(uk, u2r[0][k], s0);                                    \
              s1 = fmaf(uk, u2r[1][k], s1);                                    \
              s2 = fmaf(uk, u2r[2][k], s2);                                    \
              s3 = fmaf(uk, u2r[3][k], s3);                                    \
          }                                                                    \
          float e0 = __builtin_amdgcn_exp2f(-L2E * s0);                        \
          float e1 = __builtin_amdgcn_exp2f(-L2E * s1);                        \
          float e2 = __builtin_amdgcn_exp2f(-L2E * s2);                        \
          float e3 = __builtin_amdgcn_exp2f(-L2E * s3);                        \
          f4 a = buf[r];                                                       \
          p0 *= fmaf(a.x, e0, 1.0f);                                           \
          p1 *= fmaf(a.y, e1, 1.0f);                                           \
          p2 *= fmaf(a.z, e2, 1.0f);                                           \
          p3 *= fmaf(a.w, e3, 1.0f);                                           \
      }                                                                        \
      acc += __builtin_amdgcn_logf((p0 * p1) * (p2 * p3)); }

    LOADG(av, 0);
    #pragma unroll
    for (int gg = 0; gg < 8; ++gg) {
        LOADG(bv, 2 * gg + 1);
        COMPG(av, 2 * gg);
        if (gg < 7) LOADG(av, 2 * gg + 2);
        COMPG(bv, 2 * gg + 1);
    }
#undef LOADG
#undef COMPG

    float part = acc * 0.69314718055994531f;

    #pragma unroll
    for (int off = 32; off; off >>= 1)
        part += __shfl_down(part, off, 64);
    __shared__ float wsum[4];
    if (lane == 0) wsum[wave] = part;
    __syncthreads();
    if (t == 0)
        atomicAdd(out, wsum[0] + wsum[1] + wsum[2] + wsum[3]);
}

// DIAGNOSTIC PROBE: 5 sequential grid-stride passes over A (3.02 GB fetch).
// Forced > 383 us under every theory -> lands in rocprof top-5 with its own
// FETCH_SIZE / hbm_gbps: a direct measurement of this buffer's read BW.
// Per-pass +pass element offset defeats load CSE; addresses stay coalesced.
// Checksum -> d_ws (2 MB, never read): no DCE, no effect on out/absmax.
// (r6 fix: ext_vector_type u4, not HIP's uint4 class, for nontemporal_load.)
__global__ __launch_bounds__(256, 8)
void probe_kernel(const float* __restrict__ A, unsigned* __restrict__ sink) {
    const size_t M16 = (size_t)N_DIM * N_DIM / 4;   // u4 count
    size_t idx = (size_t)blockIdx.x * blockDim.x + threadIdx.x;
    size_t stride = (size_t)gridDim.x * blockDim.x;
    unsigned acc = 0;
    #pragma unroll 1
    for (int pass = 0; pass < PROBE_PASSES; ++pass) {
        const u4* p = (const u4*)A + pass;          // shift -> distinct addrs
        #pragma unroll 1
        for (size_t i = idx; i < M16 - PROBE_PASSES; i += stride) {
            u4 v = __builtin_nontemporal_load(p + i);
            acc ^= v.x ^ v.y ^ v.z ^ v.w;
        }
    }
    sink[idx] = acc;
}

extern "C" void kernel_launch(void* const* d_in, const int* in_sizes, int n_in,
                              void* d_out, int out_size, void* d_ws, size_t ws_size,
                              hipStream_t stream) {
    const float* A    = (const float*)d_in[0];
    const float* U1   = (const float*)d_in[1];
    const float* U2   = (const float*)d_in[2];
    const float* lmbd = (const float*)d_in[3];
    float* out = (float*)d_out;
    unsigned* sink = (unsigned*)((char*)d_ws + PROBE_OFF);

    zero_kernel<<<1, 64, 0, stream>>>(out);
    l1_kernel<<<256, 256, 0, stream>>>(U1, U2, lmbd, out);

    dim3 grid(NTILE, NTILE);            // 48 x 48 = 2304 blocks
    loss_kernel<<<grid, 256, 0, stream>>>(A, U1, U2, out);

    probe_kernel<<<2048, 256, 0, stream>>>(A, sink);   // diagnostic only
}

// Round 8
// 747.800 us; speedup vs baseline: 1.5907x; 1.5907x over previous
//
#include <hip/hip_runtime.h>

#define N_DIM 12288
#define D_DIM 16
#define TILE  256               // 256x256 tile of A per block
#define NTILE (N_DIM / TILE)    // 48 -> 2304 blocks

typedef float f4 __attribute__((ext_vector_type(4)));

// out[0] = 0 (d_out is poisoned 0xAA before every timed call)
__global__ void zero_kernel(float* __restrict__ out) {
    out[0] = 0.0f;
}

// lmbd1 * (sum|U1| + sum|U2|)
__global__ void l1_kernel(const float* __restrict__ U1,
                          const float* __restrict__ U2,
                          const float* __restrict__ lmbd,
                          float* __restrict__ out) {
    const int M = N_DIM * D_DIM;
    int idx = blockIdx.x * blockDim.x + threadIdx.x;
    int stride = gridDim.x * blockDim.x;
    float s = 0.0f;
    for (int i = idx; i < M; i += stride)
        s += fabsf(U1[i]) + fabsf(U2[i]);
    #pragma unroll
    for (int off = 32; off; off >>= 1)
        s += __shfl_down(s, off, 64);
    __shared__ float ws[4];
    int lane = threadIdx.x & 63;
    int wave = threadIdx.x >> 6;
    if (lane == 0) ws[wave] = s;
    __syncthreads();
    if (threadIdx.x == 0)
        atomicAdd(out, lmbd[0] * (ws[0] + ws[1] + ws[2] + ws[3]));
}

// sum_ij A_ij * (-log_sigmoid(<U1_i,U2_j>)), single pass over A.
// Best-known structure (round 5, 747.7 us, absmax 0.0).
// SESSION FINDING (r0-r7): dur_us = fill1(~375) + max(fill2(~375), chain) --
// two in-window 2.416 GB harness poison fills (rocprof top-5, 6.3-6.5 TB/s);
// this chain (~360 us) is fully hidden under fill2. Kernel-side floor reached.
__global__ __launch_bounds__(256, 4)
void loss_kernel(const float* __restrict__ A,
                 const float* __restrict__ U1,
                 const float* __restrict__ U2,
                 float* __restrict__ out) {
    const int t    = threadIdx.x;
    const int lane = t & 63;
    const int wave = t >> 6;
    const int r0   = blockIdx.y * TILE;
    const int c0   = blockIdx.x * TILE;

    // U2 fragment: 4 columns x 16 k in 64 VGPRs (coalesced f4 loads;
    // wave covers a contiguous 16 KB span of U2).
    float u2r[4][D_DIM];
    #pragma unroll
    for (int c = 0; c < 4; ++c) {
        const f4* p = (const f4*)(U2 + (size_t)(c0 + lane * 4 + c) * D_DIM);
        f4 qa = p[0], qb = p[1], qc = p[2], qd = p[3];
        u2r[c][0]  = qa.x; u2r[c][1]  = qa.y; u2r[c][2]  = qa.z; u2r[c][3]  = qa.w;
        u2r[c][4]  = qb.x; u2r[c][5]  = qb.y; u2r[c][6]  = qb.z; u2r[c][7]  = qb.w;
        u2r[c][8]  = qc.x; u2r[c][9]  = qc.y; u2r[c][10] = qc.z; u2r[c][11] = qc.w;
        u2r[c][12] = qd.x; u2r[c][13] = qd.y; u2r[c][14] = qd.z; u2r[c][15] = qd.w;
    }

    // Wave-uniform U1 row pointer -> scalar (s_load) path.
    const int urow0 = __builtin_amdgcn_readfirstlane(r0 + wave * 64);
    const float* __restrict__ up = U1 + (size_t)urow0 * D_DIM;
    const float* __restrict__ ap =
        A + (size_t)(r0 + wave * 64) * N_DIM + (size_t)c0 + lane * 4;

    const float L2E = 1.4426950408889634f;
    float acc = 0.0f;                  // sums log2 of per-group products

    f4 av[4], bv[4];                   // statically indexed -> registers

#define LOADG(buf, g)                                                          \
    { _Pragma("unroll")                                                        \
      for (int r = 0; r < 4; ++r)                                              \
          buf[r] = __builtin_nontemporal_load(                                 \
              (const f4*)(ap + (size_t)(4 * (g) + r) * N_DIM)); }

#define COMPG(buf, g)                                                          \
    { float p0 = 1.0f, p1 = 1.0f, p2 = 1.0f, p3 = 1.0f;                        \
      _Pragma("unroll")                                                        \
      for (int r = 0; r < 4; ++r) {                                            \
          const float* u = up + (size_t)(4 * (g) + r) * D_DIM;                 \
          float s0 = 0.f, s1 = 0.f, s2 = 0.f, s3 = 0.f;                        \
          _Pragma("unroll")                                                    \
          for (int k = 0; k < D_DIM; ++k) {                                    \
              float uk = u[k];               /* uniform -> SGPR operand */     \
              s0 = fmaf(uk, u2r[0][k], s0);                                    \
              s1 = fmaf(uk, u2r[1][k], s1);                                    \
              s2 = fmaf(uk, u2r[2][k], s2);                                    \
              s3 = fmaf(uk, u2r[3][k], s3);                                    \
          }                                                                    \
          float e0 = __builtin_amdgcn_exp2f(-L2E * s0);                        \
          float e1 = __builtin_amdgcn_exp2f(-L2E * s1);                        \
          float e2 = __builtin_amdgcn_exp2f(-L2E * s2);                        \
          float e3 = __builtin_amdgcn_exp2f(-L2E * s3);                        \
          f4 a = buf[r];                                                       \
          p0 *= fmaf(a.x, e0, 1.0f);                                           \
          p1 *= fmaf(a.y, e1, 1.0f);                                           \
          p2 *= fmaf(a.z, e2, 1.0f);                                           \
          p3 *= fmaf(a.w, e3, 1.0f);                                           \
      }                                                                        \
      acc += __builtin_amdgcn_logf((p0 * p1) * (p2 * p3)); }  /* v_log_f32 */

    LOADG(av, 0);                       // prologue: rows 0..3
    #pragma unroll
    for (int gg = 0; gg < 8; ++gg) {    // 16 groups of 4 rows, in pairs
        LOADG(bv, 2 * gg + 1);          // prefetch next group (8 f4 in flight)
        COMPG(av, 2 * gg);
        if (gg < 7) LOADG(av, 2 * gg + 2);
        COMPG(bv, 2 * gg + 1);
    }
#undef LOADG
#undef COMPG

    float part = acc * 0.69314718055994531f;     // ln2: log2 -> ln

    // wave reduce -> block reduce -> one atomic per block
    #pragma unroll
    for (int off = 32; off; off >>= 1)
        part += __shfl_down(part, off, 64);
    __shared__ float wsum[4];
    if (lane == 0) wsum[wave] = part;
    __syncthreads();
    if (t == 0)
        atomicAdd(out, wsum[0] + wsum[1] + wsum[2] + wsum[3]);
}

extern "C" void kernel_launch(void* const* d_in, const int* in_sizes, int n_in,
                              void* d_out, int out_size, void* d_ws, size_t ws_size,
                              hipStream_t stream) {
    const float* A    = (const float*)d_in[0];
    const float* U1   = (const float*)d_in[1];
    const float* U2   = (const float*)d_in[2];
    const float* lmbd = (const float*)d_in[3];
    float* out = (float*)d_out;

    zero_kernel<<<1, 64, 0, stream>>>(out);
    l1_kernel<<<256, 256, 0, stream>>>(U1, U2, lmbd, out);

    dim3 grid(NTILE, NTILE);            // 48 x 48 = 2304 blocks
    loss_kernel<<<grid, 256, 0, stream>>>(A, U1, U2, out);
}